// Round 12
// baseline (116.370 us; speedup 1.0000x reference)
//
#include <hip/hip_runtime.h>

typedef unsigned short u16;
typedef __bf16 b16;
typedef b16 b16x8 __attribute__((ext_vector_type(8)));
typedef float f32x4 __attribute__((ext_vector_type(4)));
typedef u16 u16x4 __attribute__((ext_vector_type(4)));
typedef u16 u16x8 __attribute__((ext_vector_type(8)));
typedef float f4 __attribute__((ext_vector_type(4)));

#define NH 8
#define SEQ 4096
#define DM 512
#define HDIM 64
#define GM 8192      // B*S
#define GK 512       // D
#define GN 1536      // 3*D

// Q pre-scale: (1/sqrt(64)) * log2(e)  -> softmax done in exp2 domain
#define QSCALE 0.18033688011112042f
// fixed softmax bias (log2 units): upper bound on max score; p = exp2(s - SMBIAS)
#define SMBIAS 14.0f

__device__ __forceinline__ u16 f2bf(float f) {
  b16 h = (b16)f;
  return __builtin_bit_cast(u16, h);
}

__device__ __forceinline__ void gl16(const u16* g, u16* l) {
  __builtin_amdgcn_global_load_lds((const __attribute__((address_space(1))) void*)g,
                                   (__attribute__((address_space(3))) void*)l, 16, 0, 0);
}

// ---------------- fused conversions: inputs f32->bf16 and W f32->bf16 transposed -----
__global__ __launch_bounds__(256) void cvt_fused(const float* __restrict__ x,
                                                 u16* __restrict__ y,
                                                 const float* __restrict__ w,
                                                 u16* __restrict__ wt) {
  __shared__ float tile[32][33];
  int bid = blockIdx.x;
  int t = threadIdx.x;
  if (bid < 2048) {
    int i = (bid * 256 + t) * 8;
    f4 a = *(const f4*)(x + i);
    f4 b = *(const f4*)(x + i + 4);
    u16x8 o;
    o[0] = f2bf(a[0]); o[1] = f2bf(a[1]); o[2] = f2bf(a[2]); o[3] = f2bf(a[3]);
    o[4] = f2bf(b[0]); o[5] = f2bf(b[1]); o[6] = f2bf(b[2]); o[7] = f2bf(b[3]);
    *(u16x8*)(y + i) = o;
  } else {
    int q = bid - 2048;                 // 768 blocks
    int n0 = (q % 48) * 32;
    int k0 = (q / 48) * 32;
    int tn = t & 31, tk = t >> 5;
#pragma unroll
    for (int p = 0; p < 4; ++p) {
      int k = tk + p * 8;
      tile[k][tn] = w[(k0 + k) * GN + n0 + tn];
    }
    __syncthreads();
    int n_l = t >> 3, kg = (t & 7) * 4;
    u16x4 o;
#pragma unroll
    for (int i2 = 0; i2 < 4; ++i2) o[i2] = f2bf(tile[kg + i2][n_l]);
    *(u16x4*)(wt + (n0 + n_l) * GK + k0 + kg) = o;
  }
}

// ---------------- QKV GEMM: A(8192x512) x Wt(1536x512)^T -> Q,K,V (B,H,S,64) bf16 ----
// Q pre-scaled by QSCALE. Ring-3 LDS staging, counted vmcnt + RAW s_barrier.
__global__ __launch_bounds__(256, 3) void qkv_gemm(const u16* __restrict__ A,
                                                   const u16* __restrict__ Wt,
                                                   u16* __restrict__ Q,
                                                   u16* __restrict__ K,
                                                   u16* __restrict__ V) {
  __shared__ __align__(16) u16 As[3][4096];
  __shared__ __align__(16) u16 Bs[3][4096];
  int bm = blockIdx.x * 128;
  int bn = blockIdx.y * 128;
  int t = threadIdx.x;
  int lane = t & 63, w = t >> 6;
  int wr = w >> 1, wc = w & 1;
  int l15 = lane & 15, g = lane >> 4;

  f32x4 acc[4][4];
#pragma unroll
  for (int i = 0; i < 4; ++i)
#pragma unroll
    for (int j = 0; j < 4; ++j) {
      acc[i][j][0] = 0.f; acc[i][j][1] = 0.f; acc[i][j][2] = 0.f; acc[i][j][3] = 0.f;
    }

#define GSTAGE(slot, k0) do {                                                   \
    _Pragma("unroll")                                                           \
    for (int p = 0; p < 2; ++p) {                                               \
      int cid = p * 256 + t;                                                    \
      int row = cid >> 2, co = (cid & 3) * 8;                                   \
      gl16(A + (size_t)(bm + row) * GK + (k0) + co, &As[slot][cid * 8]);        \
      gl16(Wt + (size_t)(bn + row) * GK + (k0) + co, &Bs[slot][cid * 8]);       \
    }                                                                           \
  } while (0)

  GSTAGE(0, 0);
  GSTAGE(1, 32);
  int cur = 0;
  for (int kk = 0; kk < 16; ++kk) {
    asm volatile("s_waitcnt vmcnt(4)" ::: "memory");
    __builtin_amdgcn_s_barrier();
    int pk = kk + 2 < 16 ? kk + 2 : 15;
    int slot = cur + 2; if (slot >= 3) slot -= 3;
    GSTAGE(slot, pk * 32);

    b16x8 af[4], bf[4];
#pragma unroll
    for (int mi = 0; mi < 4; ++mi)
      af[mi] = *(const b16x8*)(&As[cur][(wr * 64 + mi * 16 + l15) * 32 + g * 8]);
#pragma unroll
    for (int ni = 0; ni < 4; ++ni)
      bf[ni] = *(const b16x8*)(&Bs[cur][(wc * 64 + ni * 16 + l15) * 32 + g * 8]);
    __builtin_amdgcn_s_setprio(1);
#pragma unroll
    for (int mi = 0; mi < 4; ++mi)
#pragma unroll
      for (int ni = 0; ni < 4; ++ni)
        acc[mi][ni] = __builtin_amdgcn_mfma_f32_16x16x32_bf16(af[mi], bf[ni], acc[mi][ni], 0, 0, 0);
    __builtin_amdgcn_s_setprio(0);
    cur = (cur == 2) ? 0 : cur + 1;
  }

#pragma unroll
  for (int mi = 0; mi < 4; ++mi)
#pragma unroll
    for (int ni = 0; ni < 4; ++ni) {
      int e = bn + wc * 64 + ni * 16 + l15;
      int which = e >> 9, col = e & 511;
      int h = col >> 6, dd = col & 63;
      u16* dst = which == 0 ? Q : (which == 1 ? K : V);
      float scale = (which == 0) ? QSCALE : 1.0f;
#pragma unroll
      for (int r = 0; r < 4; ++r) {
        int m = bm + wr * 64 + mi * 16 + g * 4 + r;
        int b = m >> 12, s = m & 4095;
        dst[(((b * NH + h) * SEQ) + s) * HDIM + dd] = f2bf(acc[mi][ni][r] * scale);
      }
    }
}

// ---------------- V (B,H,S,64) -> Vt (B,H,64,S), sigma-permuted per 64-seq-tile ------
__global__ __launch_bounds__(256) void transpose_v(const u16* __restrict__ V,
                                                   u16* __restrict__ Vt) {
  __shared__ u16 tl[64][72];
  int bh = blockIdx.x >> 6;
  int s0 = (blockIdx.x & 63) * 64;
  const u16* src = V + ((size_t)bh * SEQ + s0) * HDIM;
  u16* dst = Vt + (size_t)bh * HDIM * SEQ + s0;
  int t = threadIdx.x;
#pragma unroll
  for (int p = 0; p < 2; ++p) {
    int cid = p * 256 + t;
    int row = cid >> 3, ch = cid & 7;
    *(u16x8*)(&tl[row][ch * 8]) = *(const u16x8*)(src + row * HDIM + ch * 8);
  }
  __syncthreads();
#pragma unroll
  for (int p = 0; p < 4; ++p) {
    int cid = p * 256 + t;
    int dd = cid >> 4, l = cid & 15;
    u16x4 o;
#pragma unroll
    for (int c = 0; c < 4; ++c) o[c] = tl[c * 16 + l][dd];
    *(u16x4*)(dst + dd * SEQ + l * 4) = o;
  }
}

// ---------------- flash attention, causal, 128 q-rows/block, 32 rows/wave ------------
// Halves LDS traffic per unit work vs 16 rows/wave (shared kf/vf feed 2 MFMAs).
// FIXED-BIAS softmax, K/V ring-2 (global_load_lds, src-XOR swizzle), 2-deep
// pipeline QK(t+1) || PV(t). LDS 48 KB -> 3 blocks/CU. Pair-balanced mapping.
__global__ __launch_bounds__(256, 3) void attn(const u16* __restrict__ Q,
                                               const u16* __restrict__ Kv,
                                               const u16* __restrict__ Vtg,
                                               float* __restrict__ out) {
  int id = blockIdx.x;
  int bh = id & 15;
  int i = id >> 4;             // 0..31
  int qt = (i < 16) ? 31 - i : i - 16;   // q-super (128 rows); pairs sum to 66 units
  int b = bh >> 3, h = bh & 7;
  const u16* Qb = Q + (size_t)bh * SEQ * HDIM;
  const u16* Kb = Kv + (size_t)bh * SEQ * HDIM;
  const u16* Vb = Vtg + (size_t)bh * HDIM * SEQ;   // [64][4096] sigma-permuted
  int t = threadIdx.x, lane = t & 63, w = t >> 6;
  int l15 = lane & 15, g = lane >> 4;
  int qb = qt * 128;
  int qw = qb + w * 32;        // wave owns rows qw..qw+31 (2 subtiles)

  __shared__ __align__(16) u16 Ks[2][4096];
  __shared__ __align__(16) u16 Vs[2][4096];
  __shared__ __align__(16) u16 Ps[8192];     // 128 rows x 64

  int rsub = lane >> 3, cp = lane & 7;
  int ch = cp ^ rsub;
  int xorp = (l15 & 7) << 3;

  b16x8 qf[2][2];              // [subtile][ks]
#pragma unroll
  for (int sub = 0; sub < 2; ++sub)
#pragma unroll
    for (int ks = 0; ks < 2; ++ks)
      qf[sub][ks] = *(const b16x8*)(Qb + (qw + sub * 16 + l15) * HDIM + ks * 32 + g * 8);

  // ones B-fragment for row-sum MFMA
  b16x8 vone;
#pragma unroll
  for (int ii = 0; ii < 8; ++ii) vone[ii] = __builtin_bit_cast(b16, (u16)0x3F80);

  f32x4 oacc[2][4], lacc[2];
#pragma unroll
  for (int sub = 0; sub < 2; ++sub) {
#pragma unroll
    for (int ii = 0; ii < 4; ++ii) {
      oacc[sub][ii][0] = 0.f; oacc[sub][ii][1] = 0.f; oacc[sub][ii][2] = 0.f; oacc[sub][ii][3] = 0.f;
    }
    lacc[sub][0] = 0.f; lacc[sub][1] = 0.f; lacc[sub][2] = 0.f; lacc[sub][3] = 0.f;
  }

#define STAGE(slot, jj) do {                                                    \
    _Pragma("unroll")                                                           \
    for (int p = 0; p < 2; ++p) {                                               \
      int row = (w * 2 + p) * 8 + rsub;                                         \
      gl16(Kb + (size_t)((jj) + row) * HDIM + ch * 8, &Ks[slot][(w * 2 + p) * 512]); \
      gl16(Vb + (size_t)row * SEQ + (jj) + ch * 8, &Vs[slot][(w * 2 + p) * 512]);    \
    }                                                                           \
  } while (0)

  // QK^T of one tile for BOTH subtiles, shared kf reads (C-init = -SMBIAS)
#define QKT2(sx, slot) do {                                                     \
    _Pragma("unroll")                                                           \
    for (int sub = 0; sub < 2; ++sub)                                           \
      _Pragma("unroll")                                                         \
      for (int c = 0; c < 4; ++c) {                                             \
        sx[sub][c][0] = -SMBIAS; sx[sub][c][1] = -SMBIAS;                       \
        sx[sub][c][2] = -SMBIAS; sx[sub][c][3] = -SMBIAS;                       \
      }                                                                         \
    _Pragma("unroll")                                                           \
    for (int c = 0; c < 4; ++c) {                                               \
      const u16* kr = Ks[slot] + (c * 16 + l15) * 64;                           \
      b16x8 kf0 = *(const b16x8*)(kr + ((g * 8) ^ xorp));                       \
      b16x8 kf1 = *(const b16x8*)(kr + ((32 + g * 8) ^ xorp));                  \
      sx[0][c] = __builtin_amdgcn_mfma_f32_16x16x32_bf16(qf[0][0], kf0, sx[0][c], 0, 0, 0); \
      sx[1][c] = __builtin_amdgcn_mfma_f32_16x16x32_bf16(qf[1][0], kf0, sx[1][c], 0, 0, 0); \
      sx[0][c] = __builtin_amdgcn_mfma_f32_16x16x32_bf16(qf[0][1], kf1, sx[0][c], 0, 0, 0); \
      sx[1][c] = __builtin_amdgcn_mfma_f32_16x16x32_bf16(qf[1][1], kf1, sx[1][c], 0, 0, 0); \
    }                                                                           \
  } while (0)

  // mask (if diagonal) + p=exp2(s) + sigma-packed bf16 store to Ps, both subtiles
#define SMSTORE2(sx, jj) do {                                                   \
    _Pragma("unroll")                                                           \
    for (int sub = 0; sub < 2; ++sub) {                                         \
      int qsub = qw + sub * 16;                                                 \
      if ((jj) + 63 > qsub) {                                                   \
        _Pragma("unroll")                                                       \
        for (int c = 0; c < 4; ++c)                                             \
          _Pragma("unroll")                                                     \
          for (int r = 0; r < 4; ++r) {                                         \
            int col = (jj) + c * 16 + l15;                                      \
            int qq = qsub + g * 4 + r;                                          \
            if (col > qq) sx[sub][c][r] = -1e30f;                               \
          }                                                                     \
      }                                                                         \
      _Pragma("unroll")                                                         \
      for (int r = 0; r < 4; ++r) {                                             \
        u16x4 pw;                                                               \
        _Pragma("unroll")                                                       \
        for (int c = 0; c < 4; ++c)                                             \
          pw[c] = f2bf(__builtin_amdgcn_exp2f(sx[sub][c][r]));                  \
        int prow = w * 32 + sub * 16 + g * 4 + r;                               \
        *(u16x4*)(Ps + prow * 64 + ((l15 * 4) ^ ((prow & 7) << 3))) = pw;       \
      }                                                                         \
    }                                                                           \
  } while (0)

  int nt = 2 * qt + 2;

  // prologue: land tile 0, prefetch tile 1, compute P(0)
  STAGE(0, 0);
  asm volatile("s_waitcnt vmcnt(0)" ::: "memory");
  __builtin_amdgcn_s_barrier();
  STAGE(1, 64);                // nt >= 2 always
  {
    f32x4 s0[2][4];
    QKT2(s0, 0);
    SMSTORE2(s0, 0);
  }

  int cur = 0;
  for (int tt = 0; tt < nt; ++tt) {
    // STAGE(t+1) (issued last iter / prologue) must have landed
    asm volatile("s_waitcnt vmcnt(0)" ::: "memory");
    __builtin_amdgcn_s_barrier();

    // V(t) -> regs (frees Vs[cur] for STAGE(t+2)); shared across both subtiles
    b16x8 vfr[2][4];
#pragma unroll
    for (int js = 0; js < 2; ++js)
#pragma unroll
      for (int tdd = 0; tdd < 4; ++tdd)
        vfr[js][tdd] = *(const b16x8*)(Vs[cur] + (tdd * 16 + l15) * 64 + ((js * 32 + g * 8) ^ xorp));
    asm volatile("s_waitcnt lgkmcnt(0)" ::: "memory");
    __builtin_amdgcn_s_barrier();

    if (tt + 2 < nt) STAGE(cur, (tt + 2) * 64);

    bool more = (tt + 1 < nt);
    f32x4 sb[2][4];
    __builtin_amdgcn_s_setprio(1);
    if (more) QKT2(sb, cur ^ 1);            // QK(t+1): independent of PV(t)

    // PV(t): P from Ps (written last iter), V from regs; row-sum via ones-MFMA
#pragma unroll
    for (int js = 0; js < 2; ++js) {
      int eoff = (js * 32 + g * 8) ^ xorp;
      b16x8 pf0 = *(const b16x8*)(Ps + (w * 32 + l15) * 64 + eoff);
      b16x8 pf1 = *(const b16x8*)(Ps + (w * 32 + 16 + l15) * 64 + eoff);
      lacc[0] = __builtin_amdgcn_mfma_f32_16x16x32_bf16(pf0, vone, lacc[0], 0, 0, 0);
      lacc[1] = __builtin_amdgcn_mfma_f32_16x16x32_bf16(pf1, vone, lacc[1], 0, 0, 0);
#pragma unroll
      for (int tdd = 0; tdd < 4; ++tdd) {
        oacc[0][tdd] = __builtin_amdgcn_mfma_f32_16x16x32_bf16(pf0, vfr[js][tdd], oacc[0][tdd], 0, 0, 0);
        oacc[1][tdd] = __builtin_amdgcn_mfma_f32_16x16x32_bf16(pf1, vfr[js][tdd], oacc[1][tdd], 0, 0, 0);
      }
    }
    __builtin_amdgcn_s_setprio(0);

    if (more) SMSTORE2(sb, (tt + 1) * 64);  // P(t+1) -> Ps for next iter
    cur ^= 1;
  }

  // ---- epilogue (lacc holds un-normalized row sums) ----
#pragma unroll
  for (int sub = 0; sub < 2; ++sub) {
    float inv[4];
#pragma unroll
    for (int r = 0; r < 4; ++r) inv[r] = 1.0f / lacc[sub][r];
#pragma unroll
    for (int tdd = 0; tdd < 4; ++tdd)
#pragma unroll
      for (int r = 0; r < 4; ++r) {
        int q = qw + sub * 16 + g * 4 + r;
        int dd = tdd * 16 + l15;
        out[((size_t)b * SEQ + q) * DM + h * HDIM + dd] = oacc[sub][tdd][r] * inv[r];
      }
  }
}

extern "C" void kernel_launch(void* const* d_in, const int* in_sizes, int n_in,
                              void* d_out, int out_size, void* d_ws, size_t ws_size,
                              hipStream_t stream) {
  const float* x = (const float*)d_in[0];       // (2,4096,512) f32
  const float* wq = (const float*)d_in[1];      // (512,1536) f32
  float* out = (float*)d_out;                   // (2,4096,512) f32
  char* ws = (char*)d_ws;

  u16* A  = (u16*)ws;                                   // 8192x512 bf16 — reused as Vt after GEMM
  u16* Wt = (u16*)(ws + 8388608);
  u16* Qw = (u16*)(ws + 8388608 + 1572864);             // (B,H,S,64) bf16
  u16* Kw = Qw + 4194304;
  u16* Vw = Kw + 4194304;
  u16* Vt = A;                                          // (B,H,64,S) bf16, aliases A (dead after GEMM)

  cvt_fused<<<2816, 256, 0, stream>>>(x, A, wq, Wt);
  dim3 gg(64, 12);
  qkv_gemm<<<gg, 256, 0, stream>>>(A, Wt, Qw, Kw, Vw);
  transpose_v<<<1024, 256, 0, stream>>>(Vw, Vt);
  attn<<<512, 256, 0, stream>>>(Qw, Kw, Vt, out);
}

// Round 13
// 88.889 us; speedup vs baseline: 1.3092x; 1.3092x over previous
//
#include <hip/hip_runtime.h>

typedef unsigned short u16;
typedef __bf16 b16;
typedef b16 b16x8 __attribute__((ext_vector_type(8)));
typedef float f32x4 __attribute__((ext_vector_type(4)));
typedef u16 u16x4 __attribute__((ext_vector_type(4)));
typedef u16 u16x8 __attribute__((ext_vector_type(8)));
typedef float f4 __attribute__((ext_vector_type(4)));

#define NH 8
#define SEQ 4096
#define DM 512
#define HDIM 64
#define GM 8192      // B*S
#define GK 512       // D
#define GN 1536      // 3*D

// Q pre-scale: (1/sqrt(64)) * log2(e)  -> softmax done in exp2 domain
#define QSCALE 0.18033688011112042f
// fixed softmax bias (log2 units): upper bound on max score; p = exp2(s - SMBIAS)
#define SMBIAS 14.0f

__device__ __forceinline__ u16 f2bf(float f) {
  b16 h = (b16)f;
  return __builtin_bit_cast(u16, h);
}

__device__ __forceinline__ void gl16(const u16* g, u16* l) {
  __builtin_amdgcn_global_load_lds((const __attribute__((address_space(1))) void*)g,
                                   (__attribute__((address_space(3))) void*)l, 16, 0, 0);
}

// ---------------- fused conversions: inputs f32->bf16 and W f32->bf16 transposed -----
__global__ __launch_bounds__(256) void cvt_fused(const float* __restrict__ x,
                                                 u16* __restrict__ y,
                                                 const float* __restrict__ w,
                                                 u16* __restrict__ wt) {
  __shared__ float tile[32][33];
  int bid = blockIdx.x;
  int t = threadIdx.x;
  if (bid < 2048) {
    int i = (bid * 256 + t) * 8;
    f4 a = *(const f4*)(x + i);
    f4 b = *(const f4*)(x + i + 4);
    u16x8 o;
    o[0] = f2bf(a[0]); o[1] = f2bf(a[1]); o[2] = f2bf(a[2]); o[3] = f2bf(a[3]);
    o[4] = f2bf(b[0]); o[5] = f2bf(b[1]); o[6] = f2bf(b[2]); o[7] = f2bf(b[3]);
    *(u16x8*)(y + i) = o;
  } else {
    int q = bid - 2048;                 // 768 blocks
    int n0 = (q % 48) * 32;
    int k0 = (q / 48) * 32;
    int tn = t & 31, tk = t >> 5;
#pragma unroll
    for (int p = 0; p < 4; ++p) {
      int k = tk + p * 8;
      tile[k][tn] = w[(k0 + k) * GN + n0 + tn];
    }
    __syncthreads();
    int n_l = t >> 3, kg = (t & 7) * 4;
    u16x4 o;
#pragma unroll
    for (int i2 = 0; i2 < 4; ++i2) o[i2] = f2bf(tile[kg + i2][n_l]);
    *(u16x4*)(wt + (n0 + n_l) * GK + k0 + kg) = o;
  }
}

// ---------------- QKV GEMM: A(8192x512) x Wt(1536x512)^T -> Q,K,V (B,H,S,64) bf16 ----
// Q pre-scaled by QSCALE. Ring-3 LDS staging, counted vmcnt + RAW s_barrier.
__global__ __launch_bounds__(256, 3) void qkv_gemm(const u16* __restrict__ A,
                                                   const u16* __restrict__ Wt,
                                                   u16* __restrict__ Q,
                                                   u16* __restrict__ K,
                                                   u16* __restrict__ V) {
  __shared__ __align__(16) u16 As[3][4096];
  __shared__ __align__(16) u16 Bs[3][4096];
  int bm = blockIdx.x * 128;
  int bn = blockIdx.y * 128;
  int t = threadIdx.x;
  int lane = t & 63, w = t >> 6;
  int wr = w >> 1, wc = w & 1;
  int l15 = lane & 15, g = lane >> 4;

  f32x4 acc[4][4];
#pragma unroll
  for (int i = 0; i < 4; ++i)
#pragma unroll
    for (int j = 0; j < 4; ++j) {
      acc[i][j][0] = 0.f; acc[i][j][1] = 0.f; acc[i][j][2] = 0.f; acc[i][j][3] = 0.f;
    }

#define GSTAGE(slot, k0) do {                                                   \
    _Pragma("unroll")                                                           \
    for (int p = 0; p < 2; ++p) {                                               \
      int cid = p * 256 + t;                                                    \
      int row = cid >> 2, co = (cid & 3) * 8;                                   \
      gl16(A + (size_t)(bm + row) * GK + (k0) + co, &As[slot][cid * 8]);        \
      gl16(Wt + (size_t)(bn + row) * GK + (k0) + co, &Bs[slot][cid * 8]);       \
    }                                                                           \
  } while (0)

  GSTAGE(0, 0);
  GSTAGE(1, 32);
  int cur = 0;
  for (int kk = 0; kk < 16; ++kk) {
    asm volatile("s_waitcnt vmcnt(4)" ::: "memory");
    __builtin_amdgcn_s_barrier();
    int pk = kk + 2 < 16 ? kk + 2 : 15;
    int slot = cur + 2; if (slot >= 3) slot -= 3;
    GSTAGE(slot, pk * 32);

    b16x8 af[4], bf[4];
#pragma unroll
    for (int mi = 0; mi < 4; ++mi)
      af[mi] = *(const b16x8*)(&As[cur][(wr * 64 + mi * 16 + l15) * 32 + g * 8]);
#pragma unroll
    for (int ni = 0; ni < 4; ++ni)
      bf[ni] = *(const b16x8*)(&Bs[cur][(wc * 64 + ni * 16 + l15) * 32 + g * 8]);
    __builtin_amdgcn_s_setprio(1);
#pragma unroll
    for (int mi = 0; mi < 4; ++mi)
#pragma unroll
      for (int ni = 0; ni < 4; ++ni)
        acc[mi][ni] = __builtin_amdgcn_mfma_f32_16x16x32_bf16(af[mi], bf[ni], acc[mi][ni], 0, 0, 0);
    __builtin_amdgcn_s_setprio(0);
    cur = (cur == 2) ? 0 : cur + 1;
  }

#pragma unroll
  for (int mi = 0; mi < 4; ++mi)
#pragma unroll
    for (int ni = 0; ni < 4; ++ni) {
      int e = bn + wc * 64 + ni * 16 + l15;
      int which = e >> 9, col = e & 511;
      int h = col >> 6, dd = col & 63;
      u16* dst = which == 0 ? Q : (which == 1 ? K : V);
      float scale = (which == 0) ? QSCALE : 1.0f;
#pragma unroll
      for (int r = 0; r < 4; ++r) {
        int m = bm + wr * 64 + mi * 16 + g * 4 + r;
        int b = m >> 12, s = m & 4095;
        dst[(((b * NH + h) * SEQ) + s) * HDIM + dd] = f2bf(acc[mi][ni][r] * scale);
      }
    }
}

// ---------------- V (B,H,S,64) -> Vt (B,H,64,S), pi-permuted per 64-seq-tile ---------
// Contraction permutation pi matches the swapped-PV B-operand's natural P layout:
// stored col S holds V row kv where S = (kv>>5)*32 + ((kv>>2)&3)*8 + ((kv>>4)&1)*4 + (kv&3).
__global__ __launch_bounds__(256) void transpose_v(const u16* __restrict__ V,
                                                   u16* __restrict__ Vt) {
  __shared__ u16 tl[64][72];
  int bh = blockIdx.x >> 6;
  int s0 = (blockIdx.x & 63) * 64;
  const u16* src = V + ((size_t)bh * SEQ + s0) * HDIM;
  u16* dst = Vt + (size_t)bh * HDIM * SEQ + s0;
  int t = threadIdx.x;
#pragma unroll
  for (int p = 0; p < 2; ++p) {
    int cid = p * 256 + t;
    int row = cid >> 3, ch = cid & 7;
    *(u16x8*)(&tl[row][ch * 8]) = *(const u16x8*)(src + row * HDIM + ch * 8);
  }
  __syncthreads();
#pragma unroll
  for (int p = 0; p < 4; ++p) {
    int cid = p * 256 + t;
    int dd = cid >> 4, idx = cid & 15;
    int c = idx >> 2, g = idx & 3;
    int base = (c >> 1) * 32 + g * 8 + (c & 1) * 4;   // kv = c*16 + g*4 + r -> col base + r
    u16x4 o;
#pragma unroll
    for (int r = 0; r < 4; ++r) o[r] = tl[c * 16 + g * 4 + r][dd];
    *(u16x4*)(dst + dd * SEQ + base) = o;
  }
}

// ---------------- flash attention, causal, 64 q-rows/block, swapped QK^T -------------
// S^T = mfma(K,Q): lane owns one q-row (q = lane&15). P converted bf16 IN-REGISTER
// (contraction permutation absorbed into V's layout) -> no P LDS roundtrip.
// O^T = mfma(V^T, P^T). K ring-2 + V ring-3, ONE barrier + ONE vmcnt per tile.
// FIXED-BIAS softmax; row-sum via ones-A MFMA (lane gets l[q] directly).
__global__ __launch_bounds__(256, 4) void attn(const u16* __restrict__ Q,
                                               const u16* __restrict__ Kv,
                                               const u16* __restrict__ Vtg,
                                               float* __restrict__ out) {
  int id = blockIdx.x;
  int bh = id & 15;
  int i = id >> 4;             // 0..63
  int j = i & 15, pp = i >> 4;
  int qt = (pp == 0) ? 63 - j : (pp == 1) ? j : (pp == 2) ? 47 - j : 16 + j;
  int b = bh >> 3, h = bh & 7;
  const u16* Qb = Q + (size_t)bh * SEQ * HDIM;
  const u16* Kb = Kv + (size_t)bh * SEQ * HDIM;
  const u16* Vb = Vtg + (size_t)bh * HDIM * SEQ;   // [64][4096] pi-permuted
  int t = threadIdx.x, lane = t & 63, w = t >> 6;
  int l15 = lane & 15, g = lane >> 4;
  int qb = qt * 64;
  int qw = qb + w * 16;

  __shared__ __align__(16) u16 Ks[2][4096];
  __shared__ __align__(16) u16 Vs[3][4096];

  int rsub = lane >> 3, cp = lane & 7;
  int ch = cp ^ rsub;
  int xorp = (l15 & 7) << 3;

  b16x8 qf[2];
#pragma unroll
  for (int ks = 0; ks < 2; ++ks)
    qf[ks] = *(const b16x8*)(Qb + (qw + l15) * HDIM + ks * 32 + g * 8);

  b16x8 vone;
#pragma unroll
  for (int ii = 0; ii < 8; ++ii) vone[ii] = __builtin_bit_cast(b16, (u16)0x3F80);

  f32x4 oaccT[4], lacc;
#pragma unroll
  for (int ii = 0; ii < 4; ++ii) {
    oaccT[ii][0] = 0.f; oaccT[ii][1] = 0.f; oaccT[ii][2] = 0.f; oaccT[ii][3] = 0.f;
    lacc[ii] = 0.f;
  }
  b16x8 ptp[2];    // P^T fragments for the current PV tile (in-register)

#define STAGE2(kslot, vslot, jj) do {                                           \
    _Pragma("unroll")                                                           \
    for (int p = 0; p < 2; ++p) {                                               \
      int row = (w * 2 + p) * 8 + rsub;                                         \
      gl16(Kb + (size_t)((jj) + row) * HDIM + ch * 8, &Ks[kslot][(w * 2 + p) * 512]); \
      gl16(Vb + (size_t)row * SEQ + (jj) + ch * 8, &Vs[vslot][(w * 2 + p) * 512]);   \
    }                                                                           \
  } while (0)

  // swapped QK^T: st[c][r] = S[kv = c*16+g*4+r][q = l15]  (C-init = -SMBIAS)
#define QKT(st, kslot) do {                                                     \
    _Pragma("unroll")                                                           \
    for (int c = 0; c < 4; ++c) {                                               \
      st[c][0] = -SMBIAS; st[c][1] = -SMBIAS; st[c][2] = -SMBIAS; st[c][3] = -SMBIAS; \
    }                                                                           \
    _Pragma("unroll")                                                           \
    for (int c = 0; c < 4; ++c) {                                               \
      const u16* kr = Ks[kslot] + (c * 16 + l15) * 64;                          \
      b16x8 kf0 = *(const b16x8*)(kr + ((g * 8) ^ xorp));                       \
      b16x8 kf1 = *(const b16x8*)(kr + ((32 + g * 8) ^ xorp));                  \
      st[c] = __builtin_amdgcn_mfma_f32_16x16x32_bf16(kf0, qf[0], st[c], 0, 0, 0); \
      st[c] = __builtin_amdgcn_mfma_f32_16x16x32_bf16(kf1, qf[1], st[c], 0, 0, 0); \
    }                                                                           \
  } while (0)

  // mask + p=exp2(st) -> bf16 packed into ptX[ks] elem (c&1)*4+r  (all in-register)
#define SMREG(st, jj, ptX) do {                                                 \
    if ((jj) + 63 > qw) {                                                       \
      int qq = qw + l15;                                                        \
      _Pragma("unroll")                                                         \
      for (int c = 0; c < 4; ++c)                                               \
        _Pragma("unroll")                                                       \
        for (int r = 0; r < 4; ++r) {                                           \
          int kvg = (jj) + c * 16 + g * 4 + r;                                  \
          if (kvg > qq) st[c][r] = -1e30f;                                      \
        }                                                                       \
    }                                                                           \
    _Pragma("unroll")                                                           \
    for (int c = 0; c < 4; ++c)                                                 \
      _Pragma("unroll")                                                         \
      for (int r = 0; r < 4; ++r)                                               \
        ptX[c >> 1][(c & 1) * 4 + r] = (b16)__builtin_amdgcn_exp2f(st[c][r]);   \
  } while (0)

  int nt = qt + 1;

  // prologue: land tile 0, prefetch tile 1, compute P(0) in-register
  STAGE2(0, 0, 0);
  asm volatile("s_waitcnt vmcnt(0)" ::: "memory");
  __builtin_amdgcn_s_barrier();
  if (nt > 1) STAGE2(1, 1, 64);
  {
    f32x4 s0[4];
    QKT(s0, 0);
    SMREG(s0, 0, ptp);
  }

  for (int tt = 0; tt < nt; ++tt) {
    // K(t+1)/V(t+1) landed (per-wave), then block-wide visibility
    asm volatile("s_waitcnt vmcnt(0)" ::: "memory");
    __builtin_amdgcn_s_barrier();

    if (tt + 2 < nt) STAGE2(tt & 1, (tt + 2) % 3, (tt + 2) * 64);

    bool more = (tt + 1 < nt);
    f32x4 st[4];
    __builtin_amdgcn_s_setprio(1);
    if (more) QKT(st, (tt + 1) & 1);        // QK(t+1), independent of PV(t)

    // PV(t): O^T += V^T(t) . P^T(t); V frags from Vs[tt%3], P from registers
    const u16* Vc = Vs[tt % 3];
#pragma unroll
    for (int ks = 0; ks < 2; ++ks) {
      int eoff = (ks * 32 + g * 8);
      lacc = __builtin_amdgcn_mfma_f32_16x16x32_bf16(vone, ptp[ks], lacc, 0, 0, 0);
#pragma unroll
      for (int tdd = 0; tdd < 4; ++tdd) {
        b16x8 vf = *(const b16x8*)(Vc + (tdd * 16 + l15) * 64 + (eoff ^ xorp));
        oaccT[tdd] = __builtin_amdgcn_mfma_f32_16x16x32_bf16(vf, ptp[ks], oaccT[tdd], 0, 0, 0);
      }
    }
    __builtin_amdgcn_s_setprio(0);

    if (more) SMREG(st, (tt + 1) * 64, ptp);  // P(t+1) -> registers for next iter
  }

  // ---- epilogue: lane owns q = qw + l15; O[q][d = tdd*16 + g*4 + r] ----
  float inv = 1.0f / lacc[0];               // all 4 rows of lacc are identical
  size_t rowbase = ((size_t)b * SEQ + qw + l15) * DM + h * HDIM;
#pragma unroll
  for (int tdd = 0; tdd < 4; ++tdd)
#pragma unroll
    for (int r = 0; r < 4; ++r)
      out[rowbase + tdd * 16 + g * 4 + r] = oaccT[tdd][r] * inv;
}

extern "C" void kernel_launch(void* const* d_in, const int* in_sizes, int n_in,
                              void* d_out, int out_size, void* d_ws, size_t ws_size,
                              hipStream_t stream) {
  const float* x = (const float*)d_in[0];       // (2,4096,512) f32
  const float* wq = (const float*)d_in[1];      // (512,1536) f32
  float* out = (float*)d_out;                   // (2,4096,512) f32
  char* ws = (char*)d_ws;

  u16* A  = (u16*)ws;                                   // 8192x512 bf16 — reused as Vt after GEMM
  u16* Wt = (u16*)(ws + 8388608);
  u16* Qw = (u16*)(ws + 8388608 + 1572864);             // (B,H,S,64) bf16
  u16* Kw = Qw + 4194304;
  u16* Vw = Kw + 4194304;
  u16* Vt = A;                                          // (B,H,64,S) bf16, aliases A (dead after GEMM)

  cvt_fused<<<2816, 256, 0, stream>>>(x, A, wq, Wt);
  dim3 gg(64, 12);
  qkv_gemm<<<gg, 256, 0, stream>>>(A, Wt, Qw, Kw, Vw);
  transpose_v<<<1024, 256, 0, stream>>>(Vw, Vt);
  attn<<<1024, 256, 0, stream>>>(Qw, Kw, Vt, out);
}